// Round 2
// baseline (129.429 us; speedup 1.0000x reference)
//
#include <hip/hip_runtime.h>

#define NA   512      // atoms per batch
#define NB   4        // batches
#define NZT  95       // table size per species dim

// d_ws layout:
//   [0, NZT*NZT*25*sizeof(float4))   fused table: per (zi,zj), 25 x {c6, cni_ref, cnj_refT, 0}
//   [FUSED_BYTES, +NB*NA*4)          cn array
#define FUSED_ELEMS (NZT * NZT * 25)            // float4 entries
#define FUSED_BYTES (FUSED_ELEMS * 16)          // 3,610,000 B (16B aligned)

// ---------------------------------------------------------------------------
// Kernel 0: build fused interleaved table in ws.
// One thread per (zi,zj,k) entry; k = a*5+b2.
// ---------------------------------------------------------------------------
__global__ void __launch_bounds__(256) fuse_kernel(
    const float* __restrict__ c6ab,     // (NZT, NZT, 5, 5)
    const float* __restrict__ cn_ref,   // (NZT, NZT, 5, 5)
    float4*      __restrict__ fused)    // (NZT*NZT*25,)
{
    const int idx = blockIdx.x * 256 + threadIdx.x;
    if (idx >= FUSED_ELEMS) return;
    const int pair = idx / 25;          // zi*NZT+zj
    const int k    = idx - pair * 25;
    const int a    = k / 5;
    const int b2   = k - a * 5;
    const int zi   = pair / NZT;
    const int zj   = pair - zi * NZT;

    const float c6 = c6ab[(size_t)pair * 25 + k];
    const float ci = cn_ref[(size_t)pair * 25 + k];
    // swapaxes(-1,-2) of cn_ref[zj,zi]
    const float cj = cn_ref[((size_t)zj * NZT + zi) * 25 + b2 * 5 + a];
    fused[idx] = make_float4(c6, ci, cj, 0.0f);
}

// ---------------------------------------------------------------------------
// Kernel 1: coordination numbers cn[b*NA+i]. One 256-thread block per atom,
// each thread handles 2 j's. Block 0 also zero-inits out[].
// ---------------------------------------------------------------------------
__global__ void __launch_bounds__(256) cn_kernel(
    const float* __restrict__ coord,    // (NB, NA, 3)
    const int*   __restrict__ numbers,  // (NB, NA)
    const float* __restrict__ rcov,     // (NZT,)
    float*       __restrict__ cn,       // (NB*NA,)
    float*       __restrict__ out)      // (NB,) -- zero-init here
{
    const int bi = blockIdx.x;              // 0 .. NB*NA-1
    const int b  = bi >> 9;
    const int i  = bi & (NA - 1);

    if (bi == 0 && threadIdx.x < NB) out[threadIdx.x] = 0.0f;

    const float* cb = coord   + (size_t)b * NA * 3;
    const int*   nb = numbers + (size_t)b * NA;

    const float xi  = cb[3 * i + 0];
    const float yi  = cb[3 * i + 1];
    const float zi  = cb[3 * i + 2];
    const float rci = rcov[nb[i]];

    float acc = 0.0f;
    #pragma unroll
    for (int t = 0; t < 2; ++t) {
        const int j = threadIdx.x + t * 256;
        if (j == i) continue;
        const float dx = xi - cb[3 * j + 0];
        const float dy = yi - cb[3 * j + 1];
        const float dz = zi - cb[3 * j + 2];
        const float r2 = dx * dx + dy * dy + dz * dz;
        const float r_ang = sqrtf(r2);
        if (r_ang <= 15.0f) {
            const float rb  = r_ang * 1.8897261258369282f;   // bohr
            const float rco = rci + rcov[nb[j]];
            acc += 1.0f / (1.0f + __expf(-16.0f * (rco / rb - 1.0f)));
        }
    }
    #pragma unroll
    for (int off = 32; off > 0; off >>= 1)
        acc += __shfl_down(acc, off, 64);

    __shared__ float red[4];
    const int wave = threadIdx.x >> 6;
    if ((threadIdx.x & 63) == 0) red[wave] = acc;
    __syncthreads();
    if (threadIdx.x == 0) cn[bi] = red[0] + red[1] + red[2] + red[3];
}

// ---------------------------------------------------------------------------
// Kernel 2: pair energies. One thread per ordered pair (b,i,j).
// Block = 256 threads = one (b,i) with 256 consecutive j.
// Weight loop reads the fused table: 25 independent dwordx4 from one base.
// ---------------------------------------------------------------------------
__global__ void __launch_bounds__(256) energy_kernel(
    const float*  __restrict__ coord,    // (NB, NA, 3)
    const int*    __restrict__ numbers,  // (NB, NA)
    const float*  __restrict__ r4r2,     // (NZT,)
    const float4* __restrict__ fused,    // (NZT*NZT*25,)
    const float*  __restrict__ cn,       // (NB*NA,)
    float*        __restrict__ out)      // (NB,)
{
    const int tid = blockIdx.x * 256 + threadIdx.x;
    const int b   = tid >> 18;                 // / (NA*NA)
    const int rem = tid & (NA * NA - 1);
    const int i   = rem >> 9;                  // / NA
    const int j   = rem & (NA - 1);

    float e = 0.0f;
    if (i != j) {
        const float* cb = coord + (size_t)b * NA * 3;
        const float dx = cb[3 * i + 0] - cb[3 * j + 0];
        const float dy = cb[3 * i + 1] - cb[3 * j + 1];
        const float dz = cb[3 * i + 2] - cb[3 * j + 2];
        const float r2 = dx * dx + dy * dy + dz * dz;
        const float r_ang = sqrtf(r2);
        if (r_ang <= 15.0f) {
            const int* nb = numbers + (size_t)b * NA;
            const int zi = nb[i];
            const int zj = nb[j];
            const float cni = cn[b * NA + i];
            const float cnj = cn[b * NA + j];

            const float4* tp = fused + ((size_t)zi * NZT + zj) * 25;

            float wsum = 0.0f, c6w = 0.0f;
            #pragma unroll
            for (int k = 0; k < 25; ++k) {
                const float4 t = tp[k];
                const float di = cni - t.y;
                const float dj = cnj - t.z;
                float s = di * di;
                s = fmaf(dj, dj, s);
                float w = __expf(-4.0f * s);
                w = (t.x > 0.0f) ? w : 0.0f;
                wsum += w;
                c6w  = fmaf(t.x, w, c6w);
            }
            const float c6 = c6w / (wsum + 1e-20f);

            const float rrij = r4r2[zi] * r4r2[zj];
            const float c8   = 3.0f * c6 * rrij;
            const float r0   = sqrtf(3.0f * rrij);
            const float f    = 0.4145f * r0 + 4.8593f;

            const float B2  = 1.8897261258369282f * 1.8897261258369282f;
            const float r2b = r2 * B2;            // r_bohr^2
            const float r6  = r2b * r2b * r2b;    // r_bohr^6
            const float r8  = r6 * r2b;           // r_bohr^8
            const float f2  = f * f;
            const float f6  = f2 * f2 * f2;
            const float f8  = f6 * f2;

            float ep = c6 / (r6 + f6) + 1.2177f * c8 / (r8 + f8);

            // smooth cutoff switch on r_ang in [12, 15]
            float x = (r_ang - 12.0f) * (1.0f / 3.0f);
            x = fminf(fmaxf(x, 0.0f), 1.0f);
            const float sw = 1.0f - x * x * (3.0f - 2.0f * x);
            e = ep * sw;
        }
    }

    // block reduction: wave shuffle then cross-wave via LDS
    #pragma unroll
    for (int off = 32; off > 0; off >>= 1)
        e += __shfl_down(e, off, 64);

    __shared__ float red[4];
    const int wave = threadIdx.x >> 6;
    if ((threadIdx.x & 63) == 0) red[wave] = e;
    __syncthreads();
    if (threadIdx.x == 0) {
        const float s = red[0] + red[1] + red[2] + red[3];
        atomicAdd(&out[b], s * (-0.5f * 27.211386245988f));
    }
}

// ---------------------------------------------------------------------------
extern "C" void kernel_launch(void* const* d_in, const int* in_sizes, int n_in,
                              void* d_out, int out_size, void* d_ws, size_t ws_size,
                              hipStream_t stream) {
    const float* coord   = (const float*)d_in[0];
    const int*   numbers = (const int*)  d_in[1];
    const float* rcov    = (const float*)d_in[2];
    const float* r4r2    = (const float*)d_in[3];
    const float* c6ab    = (const float*)d_in[4];
    const float* cn_ref  = (const float*)d_in[5];
    float* out = (float*)d_out;

    float4* fused = (float4*)d_ws;
    float*  cn    = (float*)((char*)d_ws + FUSED_BYTES);

    fuse_kernel<<<(FUSED_ELEMS + 255) / 256, 256, 0, stream>>>(c6ab, cn_ref, fused);

    cn_kernel<<<NB * NA, 256, 0, stream>>>(coord, numbers, rcov, cn, out);

    const int total = NB * NA * NA;
    energy_kernel<<<total / 256, 256, 0, stream>>>(coord, numbers, r4r2, fused,
                                                   cn, out);
}

// Round 3
// 128.951 us; speedup vs baseline: 1.0037x; 1.0037x over previous
//
#include <hip/hip_runtime.h>

#define NA   512      // atoms per batch
#define NB   4        // batches
#define NZT  95       // table size per species dim

#define FUSED_ELEMS (NZT * NZT * 25)            // float4 entries
#define FUSED_BYTES (FUSED_ELEMS * 16)          // 3,610,000 B
#define FUSE_BLOCKS ((FUSED_ELEMS + 255) / 256) // 882

// ws layout (bytes), 64B-aligned sections:
//   [0, FUSED_BYTES)        fused table
//   [SORT_OFF, ...)         sorted SoA arrays, each NB*NA = 2048 elems
#define SORT_OFF (((FUSED_BYTES + 63) / 64) * 64)
#define ARR_B    (NB * NA * 4)                  // 8192 B per array

// ---------------------------------------------------------------------------
// Kernel 0 (prep): blocks 0..NB-1 species-sort each batch (counting sort,
// order within a species irrelevant — energy is permutation-invariant);
// remaining blocks build the fused interleaved table
// {c6, cni_ref, cnj_refT, 0} per (zi,zj,k).
// ---------------------------------------------------------------------------
__global__ void __launch_bounds__(256) prep_kernel(
    const float* __restrict__ coord,    // (NB, NA, 3)
    const int*   __restrict__ numbers,  // (NB, NA)
    const float* __restrict__ rcov,     // (NZT,)
    const float* __restrict__ r4r2,     // (NZT,)
    const float* __restrict__ c6ab,     // (NZT, NZT, 5, 5)
    const float* __restrict__ cn_ref,   // (NZT, NZT, 5, 5)
    float4*      __restrict__ fused,    // (NZT*NZT*25,)
    float*       __restrict__ xs,       // sorted SoA coords
    float*       __restrict__ ys,
    float*       __restrict__ zs,
    float*       __restrict__ rcs,      // sorted rcov[z]
    float*       __restrict__ rrs,      // sorted r4r2[z]
    int*         __restrict__ zsp,      // sorted species
    float*       __restrict__ out)      // (NB,) -- zero-init here
{
    const int blk = blockIdx.x;
    if (blk < NB) {
        // ---- counting sort of batch `blk` by species ----
        const int b = blk;
        __shared__ int hist[NZT];
        __shared__ int offs[NZT];
        for (int t = threadIdx.x; t < NZT; t += 256) hist[t] = 0;
        if (blk == 0 && threadIdx.x < NB) out[threadIdx.x] = 0.0f;
        __syncthreads();

        const int i0 = threadIdx.x;
        const int i1 = threadIdx.x + 256;
        const int z0 = numbers[b * NA + i0];
        const int z1 = numbers[b * NA + i1];
        atomicAdd(&hist[z0], 1);
        atomicAdd(&hist[z1], 1);
        __syncthreads();
        if (threadIdx.x == 0) {
            int s = 0;
            for (int k = 0; k < NZT; ++k) { offs[k] = s; s += hist[k]; }
        }
        __syncthreads();

        const float* cb = coord + (size_t)b * NA * 3;
        const int base = b * NA;

        const int p0 = base + atomicAdd(&offs[z0], 1);
        xs[p0]  = cb[3 * i0 + 0];
        ys[p0]  = cb[3 * i0 + 1];
        zs[p0]  = cb[3 * i0 + 2];
        rcs[p0] = rcov[z0];
        rrs[p0] = r4r2[z0];
        zsp[p0] = z0;

        const int p1 = base + atomicAdd(&offs[z1], 1);
        xs[p1]  = cb[3 * i1 + 0];
        ys[p1]  = cb[3 * i1 + 1];
        zs[p1]  = cb[3 * i1 + 2];
        rcs[p1] = rcov[z1];
        rrs[p1] = r4r2[z1];
        zsp[p1] = z1;
        return;
    }

    // ---- fused table build ----
    const int idx = (blk - NB) * 256 + threadIdx.x;
    if (idx >= FUSED_ELEMS) return;
    const int pair = idx / 25;          // zi*NZT+zj
    const int k    = idx - pair * 25;
    const int a    = k / 5;
    const int b2   = k - a * 5;
    const int zi   = pair / NZT;
    const int zj   = pair - zi * NZT;

    const float c6 = c6ab[(size_t)pair * 25 + k];
    const float ci = cn_ref[(size_t)pair * 25 + k];
    const float cj = cn_ref[((size_t)zj * NZT + zi) * 25 + b2 * 5 + a]; // swapaxes
    fused[idx] = make_float4(c6, ci, cj, 0.0f);
}

// ---------------------------------------------------------------------------
// Kernel 1: coordination numbers in sorted space. One 256-thread block per
// sorted atom; all loads coalesced from the sorted SoA arrays.
// ---------------------------------------------------------------------------
__global__ void __launch_bounds__(256) cn_kernel(
    const float* __restrict__ xs,
    const float* __restrict__ ys,
    const float* __restrict__ zs,
    const float* __restrict__ rcs,
    float*       __restrict__ cn)       // (NB*NA,)
{
    const int bi   = blockIdx.x;            // 0 .. NB*NA-1
    const int b    = bi >> 9;
    const int i    = bi & (NA - 1);
    const int base = b * NA;

    const float xi  = xs[base + i];
    const float yi  = ys[base + i];
    const float zi  = zs[base + i];
    const float rci = rcs[base + i];

    float acc = 0.0f;
    #pragma unroll
    for (int t = 0; t < 2; ++t) {
        const int j = threadIdx.x + t * 256;
        if (j == i) continue;
        const float dx = xi - xs[base + j];
        const float dy = yi - ys[base + j];
        const float dz = zi - zs[base + j];
        const float r2 = dx * dx + dy * dy + dz * dz;
        const float r_ang = sqrtf(r2);
        if (r_ang <= 15.0f) {
            const float rb  = r_ang * 1.8897261258369282f;   // bohr
            const float rco = rci + rcs[base + j];
            acc += 1.0f / (1.0f + __expf(-16.0f * (rco / rb - 1.0f)));
        }
    }
    #pragma unroll
    for (int off = 32; off > 0; off >>= 1)
        acc += __shfl_down(acc, off, 64);

    __shared__ float red[4];
    const int wave = threadIdx.x >> 6;
    if ((threadIdx.x & 63) == 0) red[wave] = acc;
    __syncthreads();
    if (threadIdx.x == 0) cn[bi] = red[0] + red[1] + red[2] + red[3];
}

// ---------------------------------------------------------------------------
// Kernel 2: pair energies in sorted space. One thread per ordered pair.
// Block = one (b,i) with 256 consecutive sorted j: zj is sorted, so the
// per-lane table-row addresses form runs -> gathers coalesce ~6-10x.
// ---------------------------------------------------------------------------
__global__ void __launch_bounds__(256) energy_kernel(
    const float*  __restrict__ xs,
    const float*  __restrict__ ys,
    const float*  __restrict__ zs,
    const float*  __restrict__ rrs,
    const int*    __restrict__ zsp,
    const float4* __restrict__ fused,
    const float*  __restrict__ cn,
    float*        __restrict__ out)
{
    const int tid  = blockIdx.x * 256 + threadIdx.x;
    const int b    = tid >> 18;                 // / (NA*NA)
    const int rem  = tid & (NA * NA - 1);
    const int i    = rem >> 9;                  // block-uniform
    const int j    = rem & (NA - 1);
    const int base = b * NA;

    float e = 0.0f;
    if (i != j) {
        const float dx = xs[base + i] - xs[base + j];
        const float dy = ys[base + i] - ys[base + j];
        const float dz = zs[base + i] - zs[base + j];
        const float r2 = dx * dx + dy * dy + dz * dz;
        const float r_ang = sqrtf(r2);
        if (r_ang <= 15.0f) {
            const int zi = __builtin_amdgcn_readfirstlane(zsp[base + i]);
            const int zj = zsp[base + j];
            const float cni = cn[base + i];
            const float cnj = cn[base + j];

            const float4* tp = fused + ((size_t)zi * NZT + zj) * 25;

            float wsum = 0.0f, c6w = 0.0f;
            #pragma unroll
            for (int k = 0; k < 25; ++k) {
                const float4 t = tp[k];
                const float di = cni - t.y;
                const float dj = cnj - t.z;
                float s = di * di;
                s = fmaf(dj, dj, s);
                float w = __expf(-4.0f * s);
                w = (t.x > 0.0f) ? w : 0.0f;
                wsum += w;
                c6w  = fmaf(t.x, w, c6w);
            }
            const float c6 = c6w / (wsum + 1e-20f);

            const float rrij = rrs[base + i] * rrs[base + j];
            const float c8   = 3.0f * c6 * rrij;
            const float r0   = sqrtf(3.0f * rrij);
            const float f    = 0.4145f * r0 + 4.8593f;

            const float B2  = 1.8897261258369282f * 1.8897261258369282f;
            const float r2b = r2 * B2;            // r_bohr^2
            const float r6  = r2b * r2b * r2b;
            const float r8  = r6 * r2b;
            const float f2  = f * f;
            const float f6  = f2 * f2 * f2;
            const float f8  = f6 * f2;

            float ep = c6 / (r6 + f6) + 1.2177f * c8 / (r8 + f8);

            float x = (r_ang - 12.0f) * (1.0f / 3.0f);
            x = fminf(fmaxf(x, 0.0f), 1.0f);
            const float sw = 1.0f - x * x * (3.0f - 2.0f * x);
            e = ep * sw;
        }
    }

    #pragma unroll
    for (int off = 32; off > 0; off >>= 1)
        e += __shfl_down(e, off, 64);

    __shared__ float red[4];
    const int wave = threadIdx.x >> 6;
    if ((threadIdx.x & 63) == 0) red[wave] = e;
    __syncthreads();
    if (threadIdx.x == 0) {
        const float s = red[0] + red[1] + red[2] + red[3];
        atomicAdd(&out[b], s * (-0.5f * 27.211386245988f));
    }
}

// ---------------------------------------------------------------------------
extern "C" void kernel_launch(void* const* d_in, const int* in_sizes, int n_in,
                              void* d_out, int out_size, void* d_ws, size_t ws_size,
                              hipStream_t stream) {
    const float* coord   = (const float*)d_in[0];
    const int*   numbers = (const int*)  d_in[1];
    const float* rcov    = (const float*)d_in[2];
    const float* r4r2    = (const float*)d_in[3];
    const float* c6ab    = (const float*)d_in[4];
    const float* cn_ref  = (const float*)d_in[5];
    float* out = (float*)d_out;

    char* ws = (char*)d_ws;
    float4* fused = (float4*)ws;
    float*  xs  = (float*)(ws + SORT_OFF + 0 * ARR_B);
    float*  ys  = (float*)(ws + SORT_OFF + 1 * ARR_B);
    float*  zs  = (float*)(ws + SORT_OFF + 2 * ARR_B);
    float*  rcs = (float*)(ws + SORT_OFF + 3 * ARR_B);
    float*  rrs = (float*)(ws + SORT_OFF + 4 * ARR_B);
    int*    zsp = (int*)  (ws + SORT_OFF + 5 * ARR_B);
    float*  cn  = (float*)(ws + SORT_OFF + 6 * ARR_B);

    prep_kernel<<<NB + FUSE_BLOCKS, 256, 0, stream>>>(
        coord, numbers, rcov, r4r2, c6ab, cn_ref,
        fused, xs, ys, zs, rcs, rrs, zsp, out);

    cn_kernel<<<NB * NA, 256, 0, stream>>>(xs, ys, zs, rcs, cn);

    const int total = NB * NA * NA;
    energy_kernel<<<total / 256, 256, 0, stream>>>(xs, ys, zs, rrs, zsp,
                                                   fused, cn, out);
}

// Round 4
// 90.332 us; speedup vs baseline: 1.4328x; 1.4275x over previous
//
#include <hip/hip_runtime.h>

#define NA   512      // atoms per batch
#define NB   4        // batches
#define NZT  95       // table size per species dim

#define FUSED_ELEMS (NZT * NZT * 25)            // float4 entries
#define FUSED_BYTES (FUSED_ELEMS * 16)          // 3,610,000 B
#define FUSE_BLOCKS ((FUSED_ELEMS + 255) / 256) // 882

// ws layout (bytes), 64B-aligned sections:
//   [0, FUSED_BYTES)        fused table
//   [SORT_OFF, ...)         sorted SoA arrays, each NB*NA = 2048 elems
//   then: cn (2048 f), partials (4096 f)
#define SORT_OFF (((FUSED_BYTES + 63) / 64) * 64)
#define ARR_B    (NB * NA * 4)                  // 8192 B per array
#define EBLOCKS  (NB * NA * NA / 256)           // 4096 energy blocks

// ---------------------------------------------------------------------------
// Kernel 0 (prep): blocks 0..NB-1 species-sort each batch (counting sort,
// order within a species irrelevant — energy is permutation-invariant);
// remaining blocks build the fused interleaved table
// {c6, cni_ref, cnj_refT, 0} per (zi,zj,k).
// ---------------------------------------------------------------------------
__global__ void __launch_bounds__(256) prep_kernel(
    const float* __restrict__ coord,    // (NB, NA, 3)
    const int*   __restrict__ numbers,  // (NB, NA)
    const float* __restrict__ rcov,     // (NZT,)
    const float* __restrict__ r4r2,     // (NZT,)
    const float* __restrict__ c6ab,     // (NZT, NZT, 5, 5)
    const float* __restrict__ cn_ref,   // (NZT, NZT, 5, 5)
    float4*      __restrict__ fused,    // (NZT*NZT*25,)
    float*       __restrict__ xs,       // sorted SoA coords
    float*       __restrict__ ys,
    float*       __restrict__ zs,
    float*       __restrict__ rcs,      // sorted rcov[z]
    float*       __restrict__ rrs,      // sorted r4r2[z]
    int*         __restrict__ zsp)      // sorted species
{
    const int blk = blockIdx.x;
    if (blk < NB) {
        // ---- counting sort of batch `blk` by species ----
        const int b = blk;
        __shared__ int hist[NZT];
        __shared__ int offs[NZT];
        for (int t = threadIdx.x; t < NZT; t += 256) hist[t] = 0;
        __syncthreads();

        const int i0 = threadIdx.x;
        const int i1 = threadIdx.x + 256;
        const int z0 = numbers[b * NA + i0];
        const int z1 = numbers[b * NA + i1];
        atomicAdd(&hist[z0], 1);
        atomicAdd(&hist[z1], 1);
        __syncthreads();
        if (threadIdx.x == 0) {
            int s = 0;
            for (int k = 0; k < NZT; ++k) { offs[k] = s; s += hist[k]; }
        }
        __syncthreads();

        const float* cb = coord + (size_t)b * NA * 3;
        const int base = b * NA;

        const int p0 = base + atomicAdd(&offs[z0], 1);
        xs[p0]  = cb[3 * i0 + 0];
        ys[p0]  = cb[3 * i0 + 1];
        zs[p0]  = cb[3 * i0 + 2];
        rcs[p0] = rcov[z0];
        rrs[p0] = r4r2[z0];
        zsp[p0] = z0;

        const int p1 = base + atomicAdd(&offs[z1], 1);
        xs[p1]  = cb[3 * i1 + 0];
        ys[p1]  = cb[3 * i1 + 1];
        zs[p1]  = cb[3 * i1 + 2];
        rcs[p1] = rcov[z1];
        rrs[p1] = r4r2[z1];
        zsp[p1] = z1;
        return;
    }

    // ---- fused table build ----
    const int idx = (blk - NB) * 256 + threadIdx.x;
    if (idx >= FUSED_ELEMS) return;
    const int pair = idx / 25;          // zi*NZT+zj
    const int k    = idx - pair * 25;
    const int a    = k / 5;
    const int b2   = k - a * 5;
    const int zi   = pair / NZT;
    const int zj   = pair - zi * NZT;

    const float c6 = c6ab[(size_t)pair * 25 + k];
    const float ci = cn_ref[(size_t)pair * 25 + k];
    const float cj = cn_ref[((size_t)zj * NZT + zi) * 25 + b2 * 5 + a]; // swapaxes
    fused[idx] = make_float4(c6, ci, cj, 0.0f);
}

// ---------------------------------------------------------------------------
// Kernel 1: coordination numbers in sorted space. One 256-thread block per
// sorted atom; all loads coalesced from the sorted SoA arrays.
// ---------------------------------------------------------------------------
__global__ void __launch_bounds__(256) cn_kernel(
    const float* __restrict__ xs,
    const float* __restrict__ ys,
    const float* __restrict__ zs,
    const float* __restrict__ rcs,
    float*       __restrict__ cn)       // (NB*NA,)
{
    const int bi   = blockIdx.x;            // 0 .. NB*NA-1
    const int b    = bi >> 9;
    const int i    = bi & (NA - 1);
    const int base = b * NA;

    const float xi  = xs[base + i];
    const float yi  = ys[base + i];
    const float zi  = zs[base + i];
    const float rci = rcs[base + i];

    float acc = 0.0f;
    #pragma unroll
    for (int t = 0; t < 2; ++t) {
        const int j = threadIdx.x + t * 256;
        if (j == i) continue;
        const float dx = xi - xs[base + j];
        const float dy = yi - ys[base + j];
        const float dz = zi - zs[base + j];
        const float r2 = dx * dx + dy * dy + dz * dz;
        const float r_ang = sqrtf(r2);
        if (r_ang <= 15.0f) {
            const float rb  = r_ang * 1.8897261258369282f;   // bohr
            const float rco = rci + rcs[base + j];
            acc += 1.0f / (1.0f + __expf(-16.0f * (rco / rb - 1.0f)));
        }
    }
    #pragma unroll
    for (int off = 32; off > 0; off >>= 1)
        acc += __shfl_down(acc, off, 64);

    __shared__ float red[4];
    const int wave = threadIdx.x >> 6;
    if ((threadIdx.x & 63) == 0) red[wave] = acc;
    __syncthreads();
    if (threadIdx.x == 0) cn[bi] = red[0] + red[1] + red[2] + red[3];
}

// ---------------------------------------------------------------------------
// Kernel 2: pair energies in sorted space. One thread per ordered pair.
// IDENTICAL to R2 except: partial sum stored to partials[blockIdx.x]
// instead of a contended atomicAdd (A/B test of the atomic-serialization
// theory).
// ---------------------------------------------------------------------------
__global__ void __launch_bounds__(256) energy_kernel(
    const float*  __restrict__ xs,
    const float*  __restrict__ ys,
    const float*  __restrict__ zs,
    const float*  __restrict__ rrs,
    const int*    __restrict__ zsp,
    const float4* __restrict__ fused,
    const float*  __restrict__ cn,
    float*        __restrict__ partials) // (EBLOCKS,)
{
    const int tid  = blockIdx.x * 256 + threadIdx.x;
    const int b    = tid >> 18;                 // / (NA*NA)
    const int rem  = tid & (NA * NA - 1);
    const int i    = rem >> 9;                  // block-uniform
    const int j    = rem & (NA - 1);
    const int base = b * NA;

    float e = 0.0f;
    if (i != j) {
        const float dx = xs[base + i] - xs[base + j];
        const float dy = ys[base + i] - ys[base + j];
        const float dz = zs[base + i] - zs[base + j];
        const float r2 = dx * dx + dy * dy + dz * dz;
        const float r_ang = sqrtf(r2);
        if (r_ang <= 15.0f) {
            const int zi = __builtin_amdgcn_readfirstlane(zsp[base + i]);
            const int zj = zsp[base + j];
            const float cni = cn[base + i];
            const float cnj = cn[base + j];

            const float4* tp = fused + ((size_t)zi * NZT + zj) * 25;

            float wsum = 0.0f, c6w = 0.0f;
            #pragma unroll
            for (int k = 0; k < 25; ++k) {
                const float4 t = tp[k];
                const float di = cni - t.y;
                const float dj = cnj - t.z;
                float s = di * di;
                s = fmaf(dj, dj, s);
                float w = __expf(-4.0f * s);
                w = (t.x > 0.0f) ? w : 0.0f;
                wsum += w;
                c6w  = fmaf(t.x, w, c6w);
            }
            const float c6 = c6w / (wsum + 1e-20f);

            const float rrij = rrs[base + i] * rrs[base + j];
            const float c8   = 3.0f * c6 * rrij;
            const float r0   = sqrtf(3.0f * rrij);
            const float f    = 0.4145f * r0 + 4.8593f;

            const float B2  = 1.8897261258369282f * 1.8897261258369282f;
            const float r2b = r2 * B2;            // r_bohr^2
            const float r6  = r2b * r2b * r2b;
            const float r8  = r6 * r2b;
            const float f2  = f * f;
            const float f6  = f2 * f2 * f2;
            const float f8  = f6 * f2;

            float ep = c6 / (r6 + f6) + 1.2177f * c8 / (r8 + f8);

            float x = (r_ang - 12.0f) * (1.0f / 3.0f);
            x = fminf(fmaxf(x, 0.0f), 1.0f);
            const float sw = 1.0f - x * x * (3.0f - 2.0f * x);
            e = ep * sw;
        }
    }

    #pragma unroll
    for (int off = 32; off > 0; off >>= 1)
        e += __shfl_down(e, off, 64);

    __shared__ float red[4];
    const int wave = threadIdx.x >> 6;
    if ((threadIdx.x & 63) == 0) red[wave] = e;
    __syncthreads();
    if (threadIdx.x == 0)
        partials[blockIdx.x] = red[0] + red[1] + red[2] + red[3];
}

// ---------------------------------------------------------------------------
// Kernel 3: final reduction. NB blocks; block b sums its 1024 partials.
// ---------------------------------------------------------------------------
__global__ void __launch_bounds__(256) reduce_kernel(
    const float* __restrict__ partials,  // (EBLOCKS,)
    float*       __restrict__ out)       // (NB,)
{
    const int b = blockIdx.x;
    const int P = EBLOCKS / NB;          // 1024 partials per batch
    float s = 0.0f;
    #pragma unroll
    for (int t = 0; t < P / 256; ++t)
        s += partials[b * P + threadIdx.x + t * 256];

    #pragma unroll
    for (int off = 32; off > 0; off >>= 1)
        s += __shfl_down(s, off, 64);

    __shared__ float red[4];
    const int wave = threadIdx.x >> 6;
    if ((threadIdx.x & 63) == 0) red[wave] = s;
    __syncthreads();
    if (threadIdx.x == 0) {
        const float tot = red[0] + red[1] + red[2] + red[3];
        out[b] = tot * (-0.5f * 27.211386245988f);
    }
}

// ---------------------------------------------------------------------------
extern "C" void kernel_launch(void* const* d_in, const int* in_sizes, int n_in,
                              void* d_out, int out_size, void* d_ws, size_t ws_size,
                              hipStream_t stream) {
    const float* coord   = (const float*)d_in[0];
    const int*   numbers = (const int*)  d_in[1];
    const float* rcov    = (const float*)d_in[2];
    const float* r4r2    = (const float*)d_in[3];
    const float* c6ab    = (const float*)d_in[4];
    const float* cn_ref  = (const float*)d_in[5];
    float* out = (float*)d_out;

    char* ws = (char*)d_ws;
    float4* fused = (float4*)ws;
    float*  xs   = (float*)(ws + SORT_OFF + 0 * ARR_B);
    float*  ys   = (float*)(ws + SORT_OFF + 1 * ARR_B);
    float*  zs   = (float*)(ws + SORT_OFF + 2 * ARR_B);
    float*  rcs  = (float*)(ws + SORT_OFF + 3 * ARR_B);
    float*  rrs  = (float*)(ws + SORT_OFF + 4 * ARR_B);
    int*    zsp  = (int*)  (ws + SORT_OFF + 5 * ARR_B);
    float*  cn   = (float*)(ws + SORT_OFF + 6 * ARR_B);
    float*  part = (float*)(ws + SORT_OFF + 7 * ARR_B);  // 4096 floats

    prep_kernel<<<NB + FUSE_BLOCKS, 256, 0, stream>>>(
        coord, numbers, rcov, r4r2, c6ab, cn_ref,
        fused, xs, ys, zs, rcs, rrs, zsp);

    cn_kernel<<<NB * NA, 256, 0, stream>>>(xs, ys, zs, rcs, cn);

    energy_kernel<<<EBLOCKS, 256, 0, stream>>>(xs, ys, zs, rrs, zsp,
                                               fused, cn, part);

    reduce_kernel<<<NB, 256, 0, stream>>>(part, out);
}